// Round 5
// baseline (282.107 us; speedup 1.0000x reference)
//
#include <hip/hip_runtime.h>
#include <cstddef>
#include <cstdint>

typedef unsigned short u16;
typedef unsigned char u8;
typedef int i32x4 __attribute__((ext_vector_type(4)));
typedef int i32x8 __attribute__((ext_vector_type(8)));
typedef float f32x4 __attribute__((ext_vector_type(4)));
typedef float f32x16 __attribute__((ext_vector_type(16)));

#define M_DIM 4096
#define N_DIM 4096
#define K_DIM 512
#define NBATCH 8
#define TOT_ELEMS ((size_t)NBATCH * 4096 * 512)   // per-input element count

// ---------------- amax reduction over both tensors in one launch ----------------
__global__ void amax2_kernel(const float* __restrict__ in1, const float* __restrict__ in2,
                             unsigned* __restrict__ out) {
    const int half = gridDim.x >> 1;
    const bool first = blockIdx.x < half;
    const float4* x4 = (const float4*)(first ? in1 : in2);
    unsigned* o = out + (first ? 0 : 1);
    const int bid = first ? blockIdx.x : blockIdx.x - half;
    const size_t n4 = TOT_ELEMS / 4;
    float m = 0.0f;
    for (size_t i = (size_t)bid * blockDim.x + threadIdx.x; i < n4;
         i += (size_t)half * blockDim.x) {
        float4 v = x4[i];
        m = fmaxf(m, fmaxf(fmaxf(fabsf(v.x), fabsf(v.y)), fmaxf(fabsf(v.z), fabsf(v.w))));
    }
    #pragma unroll
    for (int off = 32; off > 0; off >>= 1)
        m = fmaxf(m, __shfl_down(m, off, 64));
    if ((threadIdx.x & 63) == 0)
        atomicMax(o, __float_as_uint(m));   // bitwise max == float max for x >= 0
}

__device__ __forceinline__ float fq_scale(unsigned bits) {
    return fmaxf(__uint_as_float(bits) / 448.0f, 1e-12f);   // max(amax/448, 1e-12)
}

// ---------------- quantize A: [B,M,K] fp32 -> fp8 bytes, same layout ----------------
__global__ void quant_a_kernel(const float* __restrict__ x, unsigned* __restrict__ q,
                               const unsigned* __restrict__ amaxbits) {
    const float scale = fq_scale(amaxbits[0]);
    const float4* x4 = (const float4*)x;
    const size_t n4 = TOT_ELEMS / 4;
    for (size_t i = (size_t)blockIdx.x * blockDim.x + threadIdx.x; i < n4;
         i += (size_t)gridDim.x * blockDim.x) {
        float4 v = x4[i];
        unsigned p = __builtin_amdgcn_cvt_pk_fp8_f32(v.x / scale, v.y / scale, 0u, false);
        p = __builtin_amdgcn_cvt_pk_fp8_f32(v.z / scale, v.w / scale, p, true);
        q[i] = p;   // 4 fp8 bytes
    }
}

// ------- quantize + transpose B: [B,K,N] fp32 -> BT [B,N,K] fp8 bytes -------
__global__ void quant_bt_kernel(const float* __restrict__ x, u8* __restrict__ bt,
                                const unsigned* __restrict__ amaxbits) {
    __shared__ __align__(16) u8 tile[64][68];
    const float scale = fq_scale(amaxbits[1]);
    const int n0 = blockIdx.x * 64, k0 = blockIdx.y * 64, b = blockIdx.z;
    const int t = threadIdx.x;                  // 256 threads
    const int cg = (t & 15) * 4;
    const float* xb = x + (size_t)b * K_DIM * N_DIM;
    #pragma unroll
    for (int r = t >> 4; r < 64; r += 16) {     // r = k index
        float4 v = *(const float4*)&xb[(size_t)(k0 + r) * N_DIM + n0 + cg];
        unsigned p01 = __builtin_amdgcn_cvt_pk_fp8_f32(v.x / scale, v.y / scale, 0u, false);
        unsigned p23 = __builtin_amdgcn_cvt_pk_fp8_f32(v.z / scale, v.w / scale, 0u, false);
        tile[cg + 0][r] = (u8)(p01 & 0xff);
        tile[cg + 1][r] = (u8)((p01 >> 8) & 0xff);
        tile[cg + 2][r] = (u8)(p23 & 0xff);
        tile[cg + 3][r] = (u8)((p23 >> 8) & 0xff);
    }
    __syncthreads();
    u8* btb = bt + (size_t)b * N_DIM * K_DIM;
    #pragma unroll
    for (int n = t >> 4; n < 64; n += 16) {     // n = output row
        uchar4 o;
        o.x = tile[n][cg + 0]; o.y = tile[n][cg + 1];
        o.z = tile[n][cg + 2]; o.w = tile[n][cg + 3];
        *(uchar4*)&btb[(size_t)(n0 + n) * K_DIM + k0 + cg] = o;
    }
}

// ---------------- GEMM: 256x256 tile, 8 K-units of 64B, counted-vmcnt pipeline ----
#define GLD_LDS16(g, l)                                                         \
    __builtin_amdgcn_global_load_lds(                                           \
        (const __attribute__((address_space(1))) void*)(g),                     \
        (__attribute__((address_space(3))) void*)(l), 16, 0, 0)

#define UNIT_LDS (256 * 128)   // one K-unit: 256 rows x (A 64B | B 64B), 32 KB
#define UNITS 8

__global__ __launch_bounds__(512, 2) void gemm_kernel(
    const u8* __restrict__ Aq, const u8* __restrict__ Bq,
    float* __restrict__ C, const unsigned* __restrict__ amaxbits) {
    __shared__ __align__(16) u8 lds[4 * UNIT_LDS];   // 128 KB, 4 unit-buffers

    const int t = threadIdx.x;
    const int w = t >> 6, l = t & 63;
    const int wr = w >> 2, wc = w & 3;      // 2M x 4N waves; per-wave out 128x64
    const int lr = l & 31, lh = l >> 5;
    const int b = blockIdx.z;

    // XCD-aware bijective swizzle (256 tiles, 8 XCDs -> 2 A-panel rows/XCD)
    const int orig = blockIdx.y * 16 + blockIdx.x;
    const int newid = (orig & 7) * 32 + (orig >> 3);
    const int by = newid >> 4, bx = newid & 15;

    const u8* Abase = Aq + (size_t)b * ((size_t)M_DIM * K_DIM) + (size_t)by * 256 * K_DIM;
    const u8* Bbase = Bq + (size_t)b * ((size_t)N_DIM * K_DIM) + (size_t)bx * 256 * K_DIM;

    // staging precompute: 2048 chunks/unit, 4 per thread
    int srcOff[4], ldsOff[4];
    bool gIsA[4];
    #pragma unroll
    for (int i = 0; i < 4; ++i) {
        const int c = t + i * 512;
        const int row = c >> 3, s = c & 7, g = s ^ (row & 7);
        ldsOff[i] = c * 16;
        srcOff[i] = row * K_DIM + (g & 3) * 16;
        gIsA[i] = (g < 4);
    }

    // fragment read offsets (swizzled)
    int aOff[4][2], bOff[2][2];
    #pragma unroll
    for (int m = 0; m < 4; ++m) {
        const int rA = wr * 128 + m * 32 + lr;
        aOff[m][0] = rA * 128 + ((lh * 2 + 0) ^ (rA & 7)) * 16;
        aOff[m][1] = rA * 128 + ((lh * 2 + 1) ^ (rA & 7)) * 16;
    }
    #pragma unroll
    for (int n = 0; n < 2; ++n) {
        const int rB = wc * 64 + n * 32 + lr;
        bOff[n][0] = rB * 128 + ((4 + lh * 2 + 0) ^ (rB & 7)) * 16;
        bOff[n][1] = rB * 128 + ((4 + lh * 2 + 1) ^ (rB & 7)) * 16;
    }

#define STAGE(uu) do {                                                          \
        const int _bb = ((uu) & 3) * UNIT_LDS;                                  \
        _Pragma("unroll")                                                       \
        for (int _i = 0; _i < 4; ++_i) {                                        \
            const u8* _src = (gIsA[_i] ? Abase : Bbase) + srcOff[_i] + (uu) * 64; \
            GLD_LDS16(_src, &lds[_bb + ldsOff[_i]]);                            \
        }                                                                       \
    } while (0)

    // prologue: 3-deep prefetch, wait only for unit 0 (counted vmcnt)
    STAGE(0); STAGE(1); STAGE(2);
    asm volatile("s_waitcnt vmcnt(8)" ::: "memory");
    __builtin_amdgcn_s_barrier();

    f32x16 acc[4][2] = {};

    #pragma unroll
    for (int u = 0; u < UNITS; ++u) {
        if (u + 3 < UNITS) STAGE(u + 3);
        const int bb = (u & 3) * UNIT_LDS;

        i32x8 af[4], bf[2];
        #pragma unroll
        for (int m = 0; m < 4; ++m) {
            i32x4 lo = *(const i32x4*)&lds[bb + aOff[m][0]];
            i32x4 hi = *(const i32x4*)&lds[bb + aOff[m][1]];
            af[m] = __builtin_shufflevector(lo, hi, 0, 1, 2, 3, 4, 5, 6, 7);
        }
        #pragma unroll
        for (int n = 0; n < 2; ++n) {
            i32x4 lo = *(const i32x4*)&lds[bb + bOff[n][0]];
            i32x4 hi = *(const i32x4*)&lds[bb + bOff[n][1]];
            bf[n] = __builtin_shufflevector(lo, hi, 0, 1, 2, 3, 4, 5, 6, 7);
        }

        asm volatile("s_waitcnt lgkmcnt(0)" ::: "memory");
        __builtin_amdgcn_sched_barrier(0);
        __builtin_amdgcn_s_setprio(1);
        #pragma unroll
        for (int m = 0; m < 4; ++m)
            #pragma unroll
            for (int n = 0; n < 2; ++n)
                acc[m][n] = __builtin_amdgcn_mfma_scale_f32_32x32x64_f8f6f4(
                    af[m], bf[n], acc[m][n], 0, 0, 0, 127, 0, 127);  // e8m0 127 = 2^0
        __builtin_amdgcn_s_setprio(0);

        if (u < 5)       asm volatile("s_waitcnt vmcnt(8)" ::: "memory");
        else if (u == 5) asm volatile("s_waitcnt vmcnt(4)" ::: "memory");
        else if (u == 6) asm volatile("s_waitcnt vmcnt(0)" ::: "memory");
        if (u < UNITS - 1) __builtin_amdgcn_s_barrier();
    }
#undef STAGE

    // ---- epilogue: C-shuffle through per-wave-private LDS slice -> dwordx4 nt ----
    // Buffers 0,1 ([0,64KB)) were last ds_read at u=4/u=5; all waves passed the
    // u=6-end barrier before any epilogue write -> no extra barrier needed.
    // Per m: write 32x64 f32 sub-tile (b32, conflict-free: 32 lanes hit 32 banks),
    // read back row-major (b128, uniform 8 dwords/bank), store 1KB/instr nt.
    const float s12 = fq_scale(amaxbits[0]) * fq_scale(amaxbits[1]);
    float* Cb = C + (size_t)b * ((size_t)M_DIM * N_DIM);
    float* slice = (float*)&lds[w * 8192];            // 8 KB private per wave
    const int fr = l >> 4, fc = (l & 15) * 4;         // readback row / col offsets
    const size_t rowbase = (size_t)by * 256 + wr * 128;
    const int colbase = bx * 256 + wc * 64;
    #pragma unroll
    for (int m = 0; m < 4; ++m) {
        #pragma unroll
        for (int n = 0; n < 2; ++n)
            #pragma unroll
            for (int r = 0; r < 16; ++r) {
                const int row = 4 * lh + (r & 3) + 8 * (r >> 2);
                slice[row * 64 + n * 32 + lr] = acc[m][n][r] * s12;
            }
        asm volatile("s_waitcnt lgkmcnt(0)" ::: "memory");
        __builtin_amdgcn_sched_barrier(0);
        #pragma unroll
        for (int i = 0; i < 8; ++i) {
            const int row = i * 4 + fr;
            f32x4 v = *(const f32x4*)&slice[row * 64 + fc];
            __builtin_nontemporal_store(
                v, (f32x4*)&Cb[(rowbase + m * 32 + row) * N_DIM + colbase + fc]);
        }
        asm volatile("s_waitcnt lgkmcnt(0)" ::: "memory");  // reads done before next m's writes
        __builtin_amdgcn_sched_barrier(0);
    }
}

// ---------------- launch ----------------
extern "C" void kernel_launch(void* const* d_in, const int* in_sizes, int n_in,
                              void* d_out, int out_size, void* d_ws, size_t ws_size,
                              hipStream_t stream) {
    const float* in1 = (const float*)d_in[0];
    const float* in2 = (const float*)d_in[1];
    float* out = (float*)d_out;

    unsigned* amax = (unsigned*)d_ws;
    u8* Aq = (u8*)((char*)d_ws + 256);
    u8* Bq = (u8*)((char*)d_ws + 256 + TOT_ELEMS);

    hipMemsetAsync(d_ws, 0, 64, stream);  // zero amax slots (ws is poisoned)

    hipLaunchKernelGGL(amax2_kernel, dim3(2048), dim3(256), 0, stream, in1, in2, amax);
    hipLaunchKernelGGL(quant_a_kernel, dim3(2048), dim3(256), 0, stream, in1,
                       (unsigned*)Aq, amax);
    hipLaunchKernelGGL(quant_bt_kernel, dim3(N_DIM / 64, K_DIM / 64, NBATCH),
                       dim3(256), 0, stream, in2, Bq, amax);
    hipLaunchKernelGGL(gemm_kernel, dim3(16, 16, NBATCH), dim3(512), 0, stream,
                       Aq, Bq, out, amax);
}

// Round 6
// 264.631 us; speedup vs baseline: 1.0660x; 1.0660x over previous
//
#include <hip/hip_runtime.h>
#include <cstddef>
#include <cstdint>

typedef unsigned short u16;
typedef unsigned char u8;
typedef int i32x4 __attribute__((ext_vector_type(4)));
typedef int i32x8 __attribute__((ext_vector_type(8)));
typedef float f32x16 __attribute__((ext_vector_type(16)));

#define M_DIM 4096
#define N_DIM 4096
#define K_DIM 512
#define NBATCH 8
#define TOT_ELEMS ((size_t)NBATCH * 4096 * 512)   // per-input element count

// ---------------- amax reduction over both tensors in one launch ----------------
__global__ void amax2_kernel(const float* __restrict__ in1, const float* __restrict__ in2,
                             unsigned* __restrict__ out) {
    const int half = gridDim.x >> 1;
    const bool first = blockIdx.x < half;
    const float4* x4 = (const float4*)(first ? in1 : in2);
    unsigned* o = out + (first ? 0 : 1);
    const int bid = first ? blockIdx.x : blockIdx.x - half;
    const size_t n4 = TOT_ELEMS / 4;
    float m = 0.0f;
    for (size_t i = (size_t)bid * blockDim.x + threadIdx.x; i < n4;
         i += (size_t)half * blockDim.x) {
        float4 v = x4[i];
        m = fmaxf(m, fmaxf(fmaxf(fabsf(v.x), fabsf(v.y)), fmaxf(fabsf(v.z), fabsf(v.w))));
    }
    #pragma unroll
    for (int off = 32; off > 0; off >>= 1)
        m = fmaxf(m, __shfl_down(m, off, 64));
    if ((threadIdx.x & 63) == 0)
        atomicMax(o, __float_as_uint(m));   // bitwise max == float max for x >= 0
}

__device__ __forceinline__ float fq_scale(unsigned bits) {
    return fmaxf(__uint_as_float(bits) / 448.0f, 1e-12f);   // max(amax/448, 1e-12)
}

// ---------------- quantize A: [B,M,K] fp32 -> fp8 bytes, same layout ----------------
__global__ void quant_a_kernel(const float* __restrict__ x, unsigned* __restrict__ q,
                               const unsigned* __restrict__ amaxbits) {
    const float scale = fq_scale(amaxbits[0]);
    const float4* x4 = (const float4*)x;
    const size_t n4 = TOT_ELEMS / 4;
    for (size_t i = (size_t)blockIdx.x * blockDim.x + threadIdx.x; i < n4;
         i += (size_t)gridDim.x * blockDim.x) {
        float4 v = x4[i];
        unsigned p = __builtin_amdgcn_cvt_pk_fp8_f32(v.x / scale, v.y / scale, 0u, false);
        p = __builtin_amdgcn_cvt_pk_fp8_f32(v.z / scale, v.w / scale, p, true);
        q[i] = p;   // 4 fp8 bytes
    }
}

// ------- quantize + transpose B: [B,K,N] fp32 -> BT [B,N,K] fp8 bytes -------
__global__ void quant_bt_kernel(const float* __restrict__ x, u8* __restrict__ bt,
                                const unsigned* __restrict__ amaxbits) {
    __shared__ __align__(16) u8 tile[64][68];
    const float scale = fq_scale(amaxbits[1]);
    const int n0 = blockIdx.x * 64, k0 = blockIdx.y * 64, b = blockIdx.z;
    const int t = threadIdx.x;                  // 256 threads
    const int cg = (t & 15) * 4;
    const float* xb = x + (size_t)b * K_DIM * N_DIM;
    #pragma unroll
    for (int r = t >> 4; r < 64; r += 16) {     // r = k index
        float4 v = *(const float4*)&xb[(size_t)(k0 + r) * N_DIM + n0 + cg];
        unsigned p01 = __builtin_amdgcn_cvt_pk_fp8_f32(v.x / scale, v.y / scale, 0u, false);
        unsigned p23 = __builtin_amdgcn_cvt_pk_fp8_f32(v.z / scale, v.w / scale, 0u, false);
        tile[cg + 0][r] = (u8)(p01 & 0xff);
        tile[cg + 1][r] = (u8)((p01 >> 8) & 0xff);
        tile[cg + 2][r] = (u8)(p23 & 0xff);
        tile[cg + 3][r] = (u8)((p23 >> 8) & 0xff);
    }
    __syncthreads();
    u8* btb = bt + (size_t)b * N_DIM * K_DIM;
    #pragma unroll
    for (int n = t >> 4; n < 64; n += 16) {     // n = output row
        uchar4 o;
        o.x = tile[n][cg + 0]; o.y = tile[n][cg + 1];
        o.z = tile[n][cg + 2]; o.w = tile[n][cg + 3];
        *(uchar4*)&btb[(size_t)(n0 + n) * K_DIM + k0 + cg] = o;
    }
}

// ------- GEMM: 256(M)x128(N) tile, 8 waves of 64x64, 2 blocks/CU for overlap -------
#define GLD_LDS16(g, l)                                                         \
    __builtin_amdgcn_global_load_lds(                                           \
        (const __attribute__((address_space(1))) void*)(g),                     \
        (__attribute__((address_space(3))) void*)(l), 16, 0, 0)

#define UNIT_LDS (384 * 64)    // one K-unit: 256 A-rows + 128 B-rows, 64 B each = 24 KB
#define UNITS 8

// Row r (64B = 4 granules): slot s holds granule g = s ^ (r&3).  r<256 -> A row r,
// r>=256 -> B row r-256.  (rule #21: linear gload_lds dest + inverse-swizzled global
// source + swizzled ds_read.)  b128 frag reads: bank = (r*16 + g*4 + w)%32 -> rows
// alternate half-banks, granules cover the rest: at the 4-dword/bank floor.
__global__ __launch_bounds__(512, 4) void gemm_kernel(
    const u8* __restrict__ Aq, const u8* __restrict__ Bq,
    float* __restrict__ C, const unsigned* __restrict__ amaxbits) {
    __shared__ __align__(16) u8 lds[2 * UNIT_LDS];   // 48 KB: 2 blocks/CU fit

    const int t = threadIdx.x;
    const int w = t >> 6, l = t & 63;
    const int wr = w >> 1, wc = w & 1;      // 4M x 2N waves; per-wave out 64x64
    const int lr = l & 31, lh = l >> 5;
    const int b = blockIdx.z;

    // XCD-aware bijective swizzle (512 tiles/batch = 8 XCDs x 64)
    const int orig = blockIdx.y * 32 + blockIdx.x;
    const int newid = (orig & 7) * 64 + (orig >> 3);
    const int by = newid >> 5, bx = newid & 31;

    const u8* Abase = Aq + (size_t)b * ((size_t)M_DIM * K_DIM) + (size_t)by * 256 * K_DIM;
    const u8* Bbase = Bq + (size_t)b * ((size_t)N_DIM * K_DIM) + (size_t)bx * 128 * K_DIM;

    // staging precompute: 1536 chunks/unit, 3 per thread
    const u8* srcPtr[3];
    int ldsOff[3];
    #pragma unroll
    for (int i = 0; i < 3; ++i) {
        const int c = t + i * 512;
        const int row = c >> 2, s = c & 3, g = s ^ (row & 3);
        ldsOff[i] = c * 16;
        srcPtr[i] = (row < 256 ? Abase + (size_t)row * K_DIM
                               : Bbase + (size_t)(row - 256) * K_DIM) + g * 16;
    }

    // fragment read offsets (swizzled); A rows 0..255, B rows 256..383
    int aOff[2][2], bOff[2][2];
    #pragma unroll
    for (int m = 0; m < 2; ++m) {
        const int rA = wr * 64 + m * 32 + lr;
        aOff[m][0] = rA * 64 + (((lh * 2 + 0) ^ (rA & 3)) & 3) * 16;
        aOff[m][1] = rA * 64 + (((lh * 2 + 1) ^ (rA & 3)) & 3) * 16;
    }
    #pragma unroll
    for (int n = 0; n < 2; ++n) {
        const int rB = 256 + wc * 64 + n * 32 + lr;
        bOff[n][0] = rB * 64 + (((lh * 2 + 0) ^ (rB & 3)) & 3) * 16;
        bOff[n][1] = rB * 64 + (((lh * 2 + 1) ^ (rB & 3)) & 3) * 16;
    }

#define STAGE(uu) do {                                                          \
        const int _bb = ((uu) & 1) * UNIT_LDS;                                  \
        _Pragma("unroll")                                                       \
        for (int _i = 0; _i < 3; ++_i)                                          \
            GLD_LDS16(srcPtr[_i] + (uu) * 64, &lds[_bb + ldsOff[_i]]);          \
    } while (0)

    STAGE(0);
    __syncthreads();   // drains vmcnt too (compiler inserts the waitcnt)

    f32x16 acc[2][2] = {};

    #pragma unroll
    for (int u = 0; u < UNITS; ++u) {
        if (u + 1 < UNITS) STAGE(u + 1);    // into the other buffer
        const int bb = (u & 1) * UNIT_LDS;

        i32x8 af[2], bf[2];
        #pragma unroll
        for (int m = 0; m < 2; ++m) {
            i32x4 lo = *(const i32x4*)&lds[bb + aOff[m][0]];
            i32x4 hi = *(const i32x4*)&lds[bb + aOff[m][1]];
            af[m] = __builtin_shufflevector(lo, hi, 0, 1, 2, 3, 4, 5, 6, 7);
        }
        #pragma unroll
        for (int n = 0; n < 2; ++n) {
            i32x4 lo = *(const i32x4*)&lds[bb + bOff[n][0]];
            i32x4 hi = *(const i32x4*)&lds[bb + bOff[n][1]];
            bf[n] = __builtin_shufflevector(lo, hi, 0, 1, 2, 3, 4, 5, 6, 7);
        }

        __builtin_amdgcn_s_setprio(1);
        #pragma unroll
        for (int m = 0; m < 2; ++m)
            #pragma unroll
            for (int n = 0; n < 2; ++n)
                acc[m][n] = __builtin_amdgcn_mfma_scale_f32_32x32x64_f8f6f4(
                    af[m], bf[n], acc[m][n], 0, 0, 0, 127, 0, 127);  // e8m0 127 = 2^0
        __builtin_amdgcn_s_setprio(0);

        __syncthreads();   // next unit staged + everyone done reading this buffer
    }
#undef STAGE

    // ---- epilogue: dequant + nt scalar stores (32x32 C/D: col=lane&31,
    // row=(r&3)+8*(r>>2)+4*lh); drains in background, overlapped by the co-resident
    // block's K-loop (the point of this round).
    const float s12 = fq_scale(amaxbits[0]) * fq_scale(amaxbits[1]);
    float* Cb = C + (size_t)b * ((size_t)M_DIM * N_DIM);
    #pragma unroll
    for (int m = 0; m < 2; ++m) {
        const int rbase = by * 256 + wr * 64 + m * 32 + 4 * lh;
        #pragma unroll
        for (int n = 0; n < 2; ++n) {
            const int col = bx * 128 + wc * 64 + n * 32 + lr;
            #pragma unroll
            for (int r = 0; r < 16; ++r) {
                const int row = rbase + (r & 3) + 8 * (r >> 2);
                __builtin_nontemporal_store(acc[m][n][r] * s12,
                                            &Cb[(size_t)row * N_DIM + col]);
            }
        }
    }
}

// ---------------- launch ----------------
extern "C" void kernel_launch(void* const* d_in, const int* in_sizes, int n_in,
                              void* d_out, int out_size, void* d_ws, size_t ws_size,
                              hipStream_t stream) {
    const float* in1 = (const float*)d_in[0];
    const float* in2 = (const float*)d_in[1];
    float* out = (float*)d_out;

    unsigned* amax = (unsigned*)d_ws;
    u8* Aq = (u8*)((char*)d_ws + 256);
    u8* Bq = (u8*)((char*)d_ws + 256 + TOT_ELEMS);

    hipMemsetAsync(d_ws, 0, 64, stream);  // zero amax slots (ws is poisoned)

    hipLaunchKernelGGL(amax2_kernel, dim3(2048), dim3(256), 0, stream, in1, in2, amax);
    hipLaunchKernelGGL(quant_a_kernel, dim3(2048), dim3(256), 0, stream, in1,
                       (unsigned*)Aq, amax);
    hipLaunchKernelGGL(quant_bt_kernel, dim3(N_DIM / 64, K_DIM / 64, NBATCH),
                       dim3(256), 0, stream, in2, Bq, amax);
    hipLaunchKernelGGL(gemm_kernel, dim3(N_DIM / 128, M_DIM / 256, NBATCH),
                       dim3(512), 0, stream, Aq, Bq, out, amax);
}

// Round 7
// 255.749 us; speedup vs baseline: 1.1031x; 1.0347x over previous
//
#include <hip/hip_runtime.h>
#include <cstddef>
#include <cstdint>

typedef unsigned short u16;
typedef unsigned char u8;
typedef int i32x4 __attribute__((ext_vector_type(4)));
typedef int i32x8 __attribute__((ext_vector_type(8)));
typedef float f32x16 __attribute__((ext_vector_type(16)));

#define M_DIM 4096
#define N_DIM 4096
#define K_DIM 512
#define NBATCH 8
#define TOT_ELEMS ((size_t)NBATCH * 4096 * 512)   // per-input element count

// ---------------- amax reduction over both tensors in one launch ----------------
__global__ void amax2_kernel(const float* __restrict__ in1, const float* __restrict__ in2,
                             unsigned* __restrict__ out) {
    const int half = gridDim.x >> 1;
    const bool first = blockIdx.x < half;
    const float4* x4 = (const float4*)(first ? in1 : in2);
    unsigned* o = out + (first ? 0 : 1);
    const int bid = first ? blockIdx.x : blockIdx.x - half;
    const size_t n4 = TOT_ELEMS / 4;
    float m = 0.0f;
    for (size_t i = (size_t)bid * blockDim.x + threadIdx.x; i < n4;
         i += (size_t)half * blockDim.x) {
        float4 v = x4[i];
        m = fmaxf(m, fmaxf(fmaxf(fabsf(v.x), fabsf(v.y)), fmaxf(fabsf(v.z), fabsf(v.w))));
    }
    #pragma unroll
    for (int off = 32; off > 0; off >>= 1)
        m = fmaxf(m, __shfl_down(m, off, 64));
    if ((threadIdx.x & 63) == 0)
        atomicMax(o, __float_as_uint(m));   // bitwise max == float max for x >= 0
}

__device__ __forceinline__ float fq_scale(unsigned bits) {
    return fmaxf(__uint_as_float(bits) / 448.0f, 1e-12f);   // max(amax/448, 1e-12)
}

// ---- fused quant: A [B,M,K]->fp8 same layout (grid-stride)  +  one BT tile/block ----
__global__ void quant_fused_kernel(const float* __restrict__ a_in,
                                   const float* __restrict__ b_in,
                                   unsigned* __restrict__ qa, u8* __restrict__ bt,
                                   const unsigned* __restrict__ amaxbits) {
    const int t = threadIdx.x;                  // 256 threads

    // ---- part 1: quantize A slice (pure stream; hides under part 2's latency) ----
    {
        const float scale = fq_scale(amaxbits[0]);
        const float4* x4 = (const float4*)a_in;
        const size_t n4 = TOT_ELEMS / 4;
        const int flat = (blockIdx.z * gridDim.y + blockIdx.y) * gridDim.x + blockIdx.x;
        const size_t nthr = (size_t)gridDim.x * gridDim.y * gridDim.z * 256;
        for (size_t i = (size_t)flat * 256 + t; i < n4; i += nthr) {
            float4 v = x4[i];
            unsigned p = __builtin_amdgcn_cvt_pk_fp8_f32(v.x / scale, v.y / scale, 0u, false);
            p = __builtin_amdgcn_cvt_pk_fp8_f32(v.z / scale, v.w / scale, p, true);
            qa[i] = p;
        }
    }

    // ---- part 2: quantize + transpose one 64x64 B tile ----
    __shared__ __align__(16) u8 tile[64][68];
    const float scale = fq_scale(amaxbits[1]);
    const int n0 = blockIdx.x * 64, k0 = blockIdx.y * 64, b = blockIdx.z;
    const int cg = (t & 15) * 4;
    const float* xb = b_in + (size_t)b * K_DIM * N_DIM;
    #pragma unroll
    for (int r = t >> 4; r < 64; r += 16) {     // r = k index
        float4 v = *(const float4*)&xb[(size_t)(k0 + r) * N_DIM + n0 + cg];
        unsigned p01 = __builtin_amdgcn_cvt_pk_fp8_f32(v.x / scale, v.y / scale, 0u, false);
        unsigned p23 = __builtin_amdgcn_cvt_pk_fp8_f32(v.z / scale, v.w / scale, 0u, false);
        tile[cg + 0][r] = (u8)(p01 & 0xff);
        tile[cg + 1][r] = (u8)((p01 >> 8) & 0xff);
        tile[cg + 2][r] = (u8)(p23 & 0xff);
        tile[cg + 3][r] = (u8)((p23 >> 8) & 0xff);
    }
    __syncthreads();
    u8* btb = bt + (size_t)b * N_DIM * K_DIM;
    #pragma unroll
    for (int n = t >> 4; n < 64; n += 16) {     // n = output row
        uchar4 o;
        o.x = tile[n][cg + 0]; o.y = tile[n][cg + 1];
        o.z = tile[n][cg + 2]; o.w = tile[n][cg + 3];
        *(uchar4*)&btb[(size_t)(n0 + n) * K_DIM + k0 + cg] = o;
    }
}

// ------- GEMM: 128x128 tile, 4 waves of 64x64, 4 blocks/CU for deep overlap -------
#define GLD_LDS16(g, l)                                                         \
    __builtin_amdgcn_global_load_lds(                                           \
        (const __attribute__((address_space(1))) void*)(g),                     \
        (__attribute__((address_space(3))) void*)(l), 16, 0, 0)

#define UNIT_LDS (256 * 64)    // one K-unit: 128 A-rows + 128 B-rows, 64 B each = 16 KB
#define UNITS 8

// Row r (64B = 4 granules): slot s holds granule g = s ^ (r&3).  r<128 -> A row r,
// r>=128 -> B row r-128.  (rule #21: linear gload_lds dest + inverse-swizzled global
// source + swizzled ds_read.)
__global__ __launch_bounds__(256, 4) void gemm_kernel(
    const u8* __restrict__ Aq, const u8* __restrict__ Bq,
    float* __restrict__ C, const unsigned* __restrict__ amaxbits) {
    __shared__ __align__(16) u8 lds[2 * UNIT_LDS];   // 32 KB -> 4 blocks/CU fit

    const int t = threadIdx.x;
    const int w = t >> 6, l = t & 63;
    const int wr = w >> 1, wc = w & 1;      // 2M x 2N waves; per-wave out 64x64
    const int lr = l & 31, lh = l >> 5;
    const int b = blockIdx.z;

    // XCD-aware bijective swizzle (1024 tiles/batch = 8 XCDs x 128)
    const int orig = blockIdx.y * 32 + blockIdx.x;
    const int newid = (orig & 7) * 128 + (orig >> 3);
    const int by = newid >> 5, bx = newid & 31;

    const u8* Abase = Aq + (size_t)b * ((size_t)M_DIM * K_DIM) + (size_t)by * 128 * K_DIM;
    const u8* Bbase = Bq + (size_t)b * ((size_t)N_DIM * K_DIM) + (size_t)bx * 128 * K_DIM;

    // staging precompute: 1024 chunks/unit, 4 per thread
    const u8* srcPtr[4];
    int ldsOff[4];
    #pragma unroll
    for (int i = 0; i < 4; ++i) {
        const int c = t + i * 256;
        const int row = c >> 2, s = c & 3, g = s ^ (row & 3);
        ldsOff[i] = c * 16;
        srcPtr[i] = (row < 128 ? Abase + (size_t)row * K_DIM
                               : Bbase + (size_t)(row - 128) * K_DIM) + g * 16;
    }

    // fragment read offsets (swizzled); A rows 0..127, B rows 128..255
    int aOff[2][2], bOff[2][2];
    #pragma unroll
    for (int m = 0; m < 2; ++m) {
        const int rA = wr * 64 + m * 32 + lr;
        aOff[m][0] = rA * 64 + (((lh * 2 + 0) ^ (rA & 3)) & 3) * 16;
        aOff[m][1] = rA * 64 + (((lh * 2 + 1) ^ (rA & 3)) & 3) * 16;
    }
    #pragma unroll
    for (int n = 0; n < 2; ++n) {
        const int rB = 128 + wc * 64 + n * 32 + lr;
        bOff[n][0] = rB * 64 + (((lh * 2 + 0) ^ (rB & 3)) & 3) * 16;
        bOff[n][1] = rB * 64 + (((lh * 2 + 1) ^ (rB & 3)) & 3) * 16;
    }

#define STAGE(uu) do {                                                          \
        const int _bb = ((uu) & 1) * UNIT_LDS;                                  \
        _Pragma("unroll")                                                       \
        for (int _i = 0; _i < 4; ++_i)                                          \
            GLD_LDS16(srcPtr[_i] + (uu) * 64, &lds[_bb + ldsOff[_i]]);          \
    } while (0)

    STAGE(0);
    __syncthreads();   // drains vmcnt too (compiler inserts the waitcnt)

    f32x16 acc[2][2] = {};

    #pragma unroll
    for (int u = 0; u < UNITS; ++u) {
        if (u + 1 < UNITS) STAGE(u + 1);    // into the other buffer
        const int bb = (u & 1) * UNIT_LDS;

        i32x8 af[2], bf[2];
        #pragma unroll
        for (int m = 0; m < 2; ++m) {
            i32x4 lo = *(const i32x4*)&lds[bb + aOff[m][0]];
            i32x4 hi = *(const i32x4*)&lds[bb + aOff[m][1]];
            af[m] = __builtin_shufflevector(lo, hi, 0, 1, 2, 3, 4, 5, 6, 7);
        }
        #pragma unroll
        for (int n = 0; n < 2; ++n) {
            i32x4 lo = *(const i32x4*)&lds[bb + bOff[n][0]];
            i32x4 hi = *(const i32x4*)&lds[bb + bOff[n][1]];
            bf[n] = __builtin_shufflevector(lo, hi, 0, 1, 2, 3, 4, 5, 6, 7);
        }

        __builtin_amdgcn_s_setprio(1);
        #pragma unroll
        for (int m = 0; m < 2; ++m)
            #pragma unroll
            for (int n = 0; n < 2; ++n)
                acc[m][n] = __builtin_amdgcn_mfma_scale_f32_32x32x64_f8f6f4(
                    af[m], bf[n], acc[m][n], 0, 0, 0, 127, 0, 127);  // e8m0 127 = 2^0
        __builtin_amdgcn_s_setprio(0);

        __syncthreads();   // next unit staged + everyone done reading this buffer
    }
#undef STAGE

    // ---- epilogue: dequant + nt scalar stores (32x32 C/D: col=lane&31,
    // row=(r&3)+8*(r>>2)+4*lh); 65 KB burst/block, drained under the 3 co-resident
    // blocks' K-loops.
    const float s12 = fq_scale(amaxbits[0]) * fq_scale(amaxbits[1]);
    float* Cb = C + (size_t)b * ((size_t)M_DIM * N_DIM);
    #pragma unroll
    for (int m = 0; m < 2; ++m) {
        const int rbase = by * 128 + wr * 64 + m * 32 + 4 * lh;
        #pragma unroll
        for (int n = 0; n < 2; ++n) {
            const int col = bx * 128 + wc * 64 + n * 32 + lr;
            #pragma unroll
            for (int r = 0; r < 16; ++r) {
                const int row = rbase + (r & 3) + 8 * (r >> 2);
                __builtin_nontemporal_store(acc[m][n][r] * s12,
                                            &Cb[(size_t)row * N_DIM + col]);
            }
        }
    }
}

// ---------------- launch ----------------
extern "C" void kernel_launch(void* const* d_in, const int* in_sizes, int n_in,
                              void* d_out, int out_size, void* d_ws, size_t ws_size,
                              hipStream_t stream) {
    const float* in1 = (const float*)d_in[0];
    const float* in2 = (const float*)d_in[1];
    float* out = (float*)d_out;

    unsigned* amax = (unsigned*)d_ws;
    u8* Aq = (u8*)((char*)d_ws + 256);
    u8* Bq = (u8*)((char*)d_ws + 256 + TOT_ELEMS);

    hipMemsetAsync(d_ws, 0, 64, stream);  // zero amax slots (ws is poisoned)

    hipLaunchKernelGGL(amax2_kernel, dim3(2048), dim3(256), 0, stream, in1, in2, amax);
    hipLaunchKernelGGL(quant_fused_kernel, dim3(N_DIM / 64, K_DIM / 64, NBATCH),
                       dim3(256), 0, stream, in1, in2, (unsigned*)Aq, Bq, amax);
    hipLaunchKernelGGL(gemm_kernel, dim3(N_DIM / 128, M_DIM / 128, NBATCH),
                       dim3(256), 0, stream, Aq, Bq, out, amax);
}